// Round 5
// baseline (410.703 us; speedup 1.0000x reference)
//
#include <hip/hip_runtime.h>
#include <hip/hip_bf16.h>

// GAT layer: out = elu( softmax(mask(leakyrelu(s1[i]+s2[j]))) @ (h@W) )
// N=8192, F_IN=512, F_OUT=64. Controllable HBM floor = adj stream (256 MiB)
// ~= 40 us. Round 5: revert to 3-kernel structure (coop launch failed
// co-residency validation); k3 redesigned with ZERO barriers in the K-loop —
// each wave self-contained: loads adj for all 16 rows of its own 64-col
// chunks, stages p via a PRIVATE LDS region (16x72 f16, pad-72 = 2-way
// conflict-free reads), MFMAs its own fragments. No cross-wave straggler
// coupling; epilogue combines once.
//
// ws: WT f16[64][512] @0 | WhT f16[64][8192] @65536 | s1 f32[8192] @1114112
//     s2 f32[8192] @1146880

typedef _Float16 f16;
typedef _Float16 f16x2 __attribute__((ext_vector_type(2)));
typedef _Float16 f16x4 __attribute__((ext_vector_type(4)));
typedef _Float16 f16x8 __attribute__((ext_vector_type(8)));
typedef float f32x4 __attribute__((ext_vector_type(4)));
typedef int   i32x4 __attribute__((ext_vector_type(4)));

#define GAT_N 8192
#define GAT_FIN 512
#define GAT_FOUT 64
#define GAT_ALPHA 0.2f

// ---------------- K0: W [512][64] f32 -> WT [64][512] f16 ----------------
__global__ void k0_wtrans(const float* __restrict__ W, f16* __restrict__ WT) {
    int idx = blockIdx.x * blockDim.x + threadIdx.x;   // 0..32767
    int k = idx >> 6, c = idx & 63;
    WT[c * GAT_FIN + k] = (f16)W[idx];
}

// ---------------- K1: Wh = h@W (f16 MFMA), fused s1/s2, emit WhT f16 -----
// 512 blocks x 4 waves; K split 4-way, partials combined via LDS.
__global__ __launch_bounds__(256) void k1_gemm(const float* __restrict__ h,
        const f16* __restrict__ WT, const float* __restrict__ a,
        f16* __restrict__ WhT, float* __restrict__ s1, float* __restrict__ s2) {
    __shared__ float pacc[4][4][64][4];     // [wave][t][lane][reg] 16 KB
    __shared__ float s1red[4][16], s2red[4][16];

    int tid = threadIdx.x;
    int w = tid >> 6, lane = tid & 63;
    int l15 = lane & 15, quad = lane >> 4;
    int rb = blockIdx.x * 16;
    size_t arow = (size_t)(rb + l15) * GAT_FIN;

    f32x4 acc[4] = {};
#pragma unroll
    for (int ks = 0; ks < 4; ks++) {
        int kb = w * 128 + ks * 32 + quad * 8;
        const float4* hp = (const float4*)(h + arow + kb);
        float4 h0 = hp[0], h1 = hp[1];
        f16x8 af = { (f16)h0.x, (f16)h0.y, (f16)h0.z, (f16)h0.w,
                     (f16)h1.x, (f16)h1.y, (f16)h1.z, (f16)h1.w };
#pragma unroll
        for (int t = 0; t < 4; t++) {
            f16x8 bf = *(const f16x8*)(WT + (t * 16 + l15) * GAT_FIN + kb);
            acc[t] = __builtin_amdgcn_mfma_f32_16x16x32_f16(af, bf, acc[t], 0, 0, 0);
        }
    }
#pragma unroll
    for (int t = 0; t < 4; t++)
        *(f32x4*)&pacc[w][t][lane][0] = acc[t];
    __syncthreads();

    float a1v = a[w * 16 + l15];
    float a2v = a[GAT_FOUT + w * 16 + l15];
    float vreg[4];
#pragma unroll
    for (int reg = 0; reg < 4; reg++) {
        float v = 0.f;
#pragma unroll
        for (int ww = 0; ww < 4; ww++) v += pacc[ww][w][lane][reg];
        vreg[reg] = v;
    }
    f16x4 pk = { (f16)vreg[0], (f16)vreg[1], (f16)vreg[2], (f16)vreg[3] };
    *(f16x4*)(WhT + (size_t)(w * 16 + l15) * GAT_N + rb + quad * 4) = pk;

#pragma unroll
    for (int reg = 0; reg < 4; reg++) {
        float c1 = vreg[reg] * a1v, c2 = vreg[reg] * a2v;
#pragma unroll
        for (int off = 1; off < 16; off <<= 1) {
            c1 += __shfl_xor(c1, off);
            c2 += __shfl_xor(c2, off);
        }
        if (l15 == 0) { s1red[w][quad * 4 + reg] = c1; s2red[w][quad * 4 + reg] = c2; }
    }
    __syncthreads();
    if (tid < 16) {
        float t1 = 0.f, t2 = 0.f;
#pragma unroll
        for (int ww = 0; ww < 4; ww++) { t1 += s1red[ww][tid]; t2 += s2red[ww][tid]; }
        s1[rb + tid] = t1;
        s2[rb + tid] = t2;
    }
}

// ---------------- K3: fused max+mask+softmax+(P@Wh)+elu ------------------
// 512 blocks (16 rows) x 8 waves. Wave w owns 64-col chunks {w, w+8, ...}:
// loads adj[16 rows][64 cols] itself (4x256-B segments/instr, nontemporal),
// computes p = exp(leakyrelu(s1+s2)-C_row)*mask, stages through a PRIVATE
// [16][72] f16 LDS region, reads its own A-frags (pad-72: 2-way, free),
// MFMAs vs L2-resident WhT. No barriers in the K-loop.
__global__ __launch_bounds__(512, 4) void k3_attn(const int* __restrict__ adj,
        const f16* __restrict__ WhT, const float* __restrict__ s1,
        const float* __restrict__ s2, float* __restrict__ out) {
    // pbuf: 8 waves x 16 x 72 f16 = 18,432 B; accbuf (32 KB) aliases it —
    // only used after the epilogue barrier.
    __shared__ __align__(16) char smem[16 * 64 * 8 * 4];   // 32 KB
    f16* pbuf = (f16*)smem;
    float (*accbuf)[16][64] = (float (*)[16][64])smem;
    __shared__ float dred[8][16];
    __shared__ float mred[8];

    int tid = threadIdx.x;
    int w = tid >> 6, lane = tid & 63;
    int l15 = lane & 15, quad = lane >> 4;
    int rb = blockIdx.x * 16;
    f16* pw = pbuf + w * (16 * 72);       // private staging region

    // ---- pre-phase: block-local max(s2); row constants cancel in num/den ----
    float m = -1e30f;
    for (int i = tid; i < GAT_N; i += 512) m = fmaxf(m, s2[i]);
#pragma unroll
    for (int off = 32; off >= 1; off >>= 1) m = fmaxf(m, __shfl_xor(m, off));
    if (lane == 0) mred[w] = m;
    __syncthreads();
    float mxv = mred[0];
#pragma unroll
    for (int ww = 1; ww < 8; ww++) mxv = fmaxf(mxv, mred[ww]);

    // row constants for the 4 rows this lane stages (rows 4i+quad)
    float s1v[4], crv[4];
#pragma unroll
    for (int i = 0; i < 4; i++) {
        float s = s1[rb + 4 * i + quad];
        s1v[i] = s;
        float c = s + mxv;
        crv[i] = fmaxf(c, GAT_ALPHA * c);
    }

    f32x4 acc[4] = {};
    float daccv[4] = { 0.f, 0.f, 0.f, 0.f };
    i32x4  av[4];
    float4 sv;

    // preload chunk w (cols w*64 ...)
    int C0 = w * 64;
#pragma unroll
    for (int i = 0; i < 4; i++)
        av[i] = __builtin_nontemporal_load(
            (const i32x4*)(adj + (size_t)(rb + 4 * i + quad) * GAT_N + C0 + l15 * 4));
    sv = *(const float4*)(s2 + C0 + l15 * 4);

    for (int ci = 0; ci < 16; ci++) {
        i32x4 avn[4];
        float4 svn;
        int C1 = C0 + 512;
        if (ci < 15) {
#pragma unroll
            for (int i = 0; i < 4; i++)
                avn[i] = __builtin_nontemporal_load(
                    (const i32x4*)(adj + (size_t)(rb + 4 * i + quad) * GAT_N + C1 + l15 * 4));
            svn = *(const float4*)(s2 + C1 + l15 * 4);
        }

        // compute p for rows 4i+quad, cols C0 + l15*4 + j; stage to private LDS
        float svv[4] = { sv.x, sv.y, sv.z, sv.w };
#pragma unroll
        for (int i = 0; i < 4; i++) {
            f16 pf[4];
#pragma unroll
            for (int j = 0; j < 4; j++) {
                float e = s1v[i] + svv[j];
                e = fmaxf(e, GAT_ALPHA * e);            // leakyrelu
                float pv = __expf(e - crv[i]);          // exponent <= ~0
                pv = (av[i][j] > 0) ? pv : 0.0f;        // mask
                daccv[i] += pv;
                pf[j] = (f16)pv;
            }
            f16x4 pk = { pf[0], pf[1], pf[2], pf[3] };
            *(f16x4*)&pw[(4 * i + quad) * 72 + l15 * 4] = pk;
        }

        // A-frags from own region (in-wave LDS order; compiler emits lgkmcnt)
#pragma unroll
        for (int sl = 0; sl < 2; sl++) {
            f16x8 af = *(const f16x8*)&pw[l15 * 72 + sl * 32 + quad * 8];
            int kb = C0 + sl * 32 + quad * 8;
#pragma unroll
            for (int t = 0; t < 4; t++) {
                f16x8 bf = *(const f16x8*)(WhT + (size_t)(t * 16 + l15) * GAT_N + kb);
                acc[t] = __builtin_amdgcn_mfma_f32_16x16x32_f16(af, bf, acc[t], 0, 0, 0);
            }
        }
#pragma unroll
        for (int i = 0; i < 4; i++) av[i] = avn[i];
        sv = svn;
        C0 = C1;
    }

    // denominator: rows 4i+quad — reduce over the 16 l15-lanes of this quad
#pragma unroll
    for (int i = 0; i < 4; i++) {
#pragma unroll
        for (int off = 1; off < 16; off <<= 1) daccv[i] += __shfl_xor(daccv[i], off);
    }
    __syncthreads();           // all waves done with pbuf; safe to alias accbuf
    if (l15 == 0) {
#pragma unroll
        for (int i = 0; i < 4; i++) dred[w][4 * i + quad] = daccv[i];
    }
    // C/D layout: acc[t][reg] = tile[row=quad*4+reg][col=t*16+l15]
#pragma unroll
    for (int t = 0; t < 4; t++)
#pragma unroll
        for (int reg = 0; reg < 4; reg++)
            accbuf[w][quad * 4 + reg][t * 16 + l15] = acc[t][reg];
    __syncthreads();

    for (int o = tid; o < 16 * 64; o += 512) {
        int rr = o >> 6, c = o & 63;
        float num = 0.f, den = 0.f;
#pragma unroll
        for (int ww = 0; ww < 8; ww++) { num += accbuf[ww][rr][c]; den += dred[ww][rr]; }
        float hp = num / den;
        out[(size_t)(rb + rr) * GAT_FOUT + c] = hp > 0.f ? hp : expm1f(hp);
    }
}

// ---------------- launch -------------------------------------------------
extern "C" void kernel_launch(void* const* d_in, const int* in_sizes, int n_in,
                              void* d_out, int out_size, void* d_ws, size_t ws_size,
                              hipStream_t stream) {
    const float* h   = (const float*)d_in[0];
    const float* W   = (const float*)d_in[1];
    const float* a   = (const float*)d_in[2];
    const int*   adj = (const int*)d_in[3];
    float* out = (float*)d_out;

    char* ws = (char*)d_ws;
    f16*   WT  = (f16*)ws;
    f16*   WhT = (f16*)(ws + 65536);
    float* s1  = (float*)(ws + 65536 + 1048576);
    float* s2  = (float*)(ws + 65536 + 1048576 + 32768);

    k0_wtrans<<<128, 256, 0, stream>>>(W, WT);
    k1_gemm<<<512, 256, 0, stream>>>(h, WT, a, WhT, s1, s2);
    k3_attn<<<512, 512, 0, stream>>>(adj, WhT, s1, s2, out);
}